// Round 7
// baseline (118.353 us; speedup 1.0000x reference)
//
#include <hip/hip_runtime.h>
#include <math.h>

#define N_SAMP 32768
#define K_COMP 2048
#define ZD 64
#define LNC 191.896324792608546f   // 64*(0.5*log(2pi) + 0.5*log(64))
#define LN2F 0.69314718055994531f
#define INV_LN2 1.44269504088896340f
// w = dot*(1/(64 ln2)) + ck2 ; wlp_nat = w*ln2 + bias_nat
#define S2C 0.02254211001388974f   // 1/(64*ln2)

#define TILES_TOT 128              // K_COMP/16
#define TPS 8                      // tiles per stage
#define STAGES (TILES_TOT / TPS)   // 16 stages
#define STAGE_B (TPS * 2048)       // 16 KB per stage (hi-only tiles = 2 KB)

typedef __attribute__((ext_vector_type(8))) short short8;
typedef __attribute__((ext_vector_type(4))) float v4f;

#if __has_builtin(__builtin_amdgcn_exp2f)
#define EXP2(x) __builtin_amdgcn_exp2f(x)
#else
#define EXP2(x) exp2f(x)
#endif

typedef const __attribute__((address_space(1))) unsigned int* gas_t;
typedef __attribute__((address_space(3))) unsigned int* las_t;
__device__ inline void gload_lds16(const void* g, void* l) {
    __builtin_amdgcn_global_load_lds((gas_t)g, (las_t)l, 16, 0, 0);
}

__device__ inline unsigned short f2bf(float f) {
    unsigned int u = __float_as_uint(f);
    u += 0x7fffu + ((u >> 16) & 1u);  // RNE
    return (unsigned short)(u >> 16);
}
__device__ inline float bf2f(unsigned short h) {
    return __uint_as_float(((unsigned int)h) << 16);
}
__device__ inline float med3f(float x, float y, float z) {
    return fmaxf(fminf(x, y), fminf(fmaxf(x, y), z));
}

// ---------------------------------------------------------------------------
// prep: blocks 0..63: locs -> bf16-HI fragment array lf (256 KB) + ck2.
//       block 64: lse = logsumexp(logits).
// lf layout: tile T (16 comps) -> 2 KB: 2 regions {d0-31, d32-63} x 64
// lanes x 16 B; mix lane l = n + 16*quad reads comp n, dims rr*32+quad*8..+8.
// prep thread: k = gid>>3, dc = gid&7 (8 dims) -> coalesced 32 B loads.
// ---------------------------------------------------------------------------
__global__ __launch_bounds__(256) void prep_kernel(
    const float* __restrict__ locs, const float* __restrict__ logits,
    float* __restrict__ ck2, float* __restrict__ lse_out,
    char* __restrict__ lf) {
    if (blockIdx.x < 64) {
        int gid = blockIdx.x * 256 + threadIdx.x;   // 0..16383
        int k = gid >> 3;
        int dc = gid & 7;
        int T = k >> 4, n = k & 15;

        const float* src = locs + (size_t)k * ZD + dc * 8;
        float4 u0 = *(const float4*)(src);
        float4 u1 = *(const float4*)(src + 4);
        float a[8] = {u0.x, u0.y, u0.z, u0.w, u1.x, u1.y, u1.z, u1.w};

        short8 h;
        float sq = 0.f;
#pragma unroll
        for (int j = 0; j < 8; ++j) {
            h[j] = (short)f2bf(a[j]);
            sq = fmaf(a[j], a[j], sq);
        }
        *(short8*)(lf + (size_t)T * 2048 + (dc >> 2) * 1024 +
                   ((size_t)(n + 16 * (dc & 3))) * 16) = h;

        // norm over the 8 consecutive lanes holding comp k
        sq += __shfl_xor(sq, 1);
        sq += __shfl_xor(sq, 2);
        sq += __shfl_xor(sq, 4);
        if (dc == 0) ck2[k] = (logits[k] - sq * (1.0f / 128.0f)) * INV_LN2;
    } else {
        __shared__ float red[4];
        int tid = threadIdx.x;
        int wv = tid >> 6, ln = tid & 63;
        float lm = -INFINITY;
        for (int i = tid; i < K_COMP; i += 256) lm = fmaxf(lm, logits[i]);
#pragma unroll
        for (int d = 1; d < 64; d <<= 1) lm = fmaxf(lm, __shfl_xor(lm, d));
        if (ln == 0) red[wv] = lm;
        __syncthreads();
        float M = fmaxf(fmaxf(red[0], red[1]), fmaxf(red[2], red[3]));
        float ls = 0.f;
        for (int i = tid; i < K_COMP; i += 256) ls += __expf(logits[i] - M);
#pragma unroll
        for (int d = 1; d < 64; d <<= 1) ls += __shfl_xor(ls, d);
        __syncthreads();
        if (ln == 0) red[wv] = ls;
        __syncthreads();
        if (tid == 0) *lse_out = M + __logf(red[0] + red[1] + red[2] + red[3]);
    }
}

// ---------------------------------------------------------------------------
// mix: block = 256 thr = 4 waves, sample-split (wave w: samples w*16..+15).
// 2-pass dot: lhi*(bhi+blo) -> w~ error sigma ~0.0013 log2. Per 16-comp
// tile: 2 ds_read_b128 + 4 MFMA + flat exp2-sum + TILE-granular top-3
// (m1,m2,m3 + quad-base indices). After the K-sweep, an exact-fp32
// resolution phase re-argmaxes the 12 candidate comps per sample.
// ---------------------------------------------------------------------------
__global__ __launch_bounds__(256, 2) void mix_kernel(
    const float* __restrict__ x, const float* __restrict__ locs,
    const char* __restrict__ lf, const float* __restrict__ ck2,
    const float* __restrict__ lse_ptr, float* __restrict__ out) {

    __shared__ char buf[2][STAGE_B];   // 2 x 16 KB
    __shared__ int cb1[64], cb2[64], cb3[64];
    __shared__ int amax_sh[64];

    const int tid  = threadIdx.x;
    const int lane = tid & 63;
    const int wv   = __builtin_amdgcn_readfirstlane(tid >> 6);  // 0..3
    const int n    = lane & 15;
    const int quad = lane >> 4;
    const int sbase = blockIdx.x * 64;
    const int srow  = sbase + wv * 16 + n;

    // ---- B fragments (x) hi/lo split; ||x||^2 exact fp32
    short8 bh0, bh1, bl0, bl1;
    float xs;
    {
        const float* xp = x + (size_t)srow * ZD + quad * 8;
        float4 u0 = *(const float4*)(xp);
        float4 u1 = *(const float4*)(xp + 4);
        float4 u2 = *(const float4*)(xp + 32);
        float4 u3 = *(const float4*)(xp + 36);
        float a[8] = {u0.x, u0.y, u0.z, u0.w, u1.x, u1.y, u1.z, u1.w};
        float b[8] = {u2.x, u2.y, u2.z, u2.w, u3.x, u3.y, u3.z, u3.w};
        float p = 0.f;
#pragma unroll
        for (int j = 0; j < 8; ++j) {
            unsigned short h;
            h = f2bf(a[j]); bh0[j] = (short)h; bl0[j] = (short)f2bf(a[j] - bf2f(h));
            h = f2bf(b[j]); bh1[j] = (short)h; bl1[j] = (short)f2bf(b[j] - bf2f(h));
            p = fmaf(a[j], a[j], p);
            p = fmaf(b[j], b[j], p);
        }
        p += __shfl_xor(p, 16);
        p += __shfl_xor(p, 32);
        xs = p;
    }

    // ---- DMA: wave wv stages tiles (S*8 + 2wv, +2wv+1): 4 KB = 4 regions
    const char* gsrc0 = lf + (size_t)wv * 4096 + lane * 16;
    char* ldst0 = &buf[0][wv * 4096];

#define DMA(S, b) do {                                                   \
    const char* _g = gsrc0 + (size_t)(S) * STAGE_B;                      \
    char* _l = ldst0 + (b) * STAGE_B;                                    \
    gload_lds16(_g, _l);                                                 \
    gload_lds16(_g + 1024, _l + 1024);                                   \
    gload_lds16(_g + 2048, _l + 2048);                                   \
    gload_lds16(_g + 3072, _l + 3072);                                   \
} while (0)

    float m1 = -1e30f, m2 = -1e30f, m3 = -1e30f;
    int i1 = 0, i2 = 0, i3 = 0;
    float s0 = 0.f, s1 = 0.f;

    DMA(0, 0);
    __syncthreads();

    for (int S = 0; S < STAGES; ++S) {
        const int b = S & 1;
        if (S + 1 < STAGES) DMA(S + 1, b ^ 1);

        const float* ckS = ck2 + S * (TPS * 16) + quad * 4;
        const char* base = &buf[b][lane * 16];
        const int kb0 = S * (TPS * 16) + quad * 4;

#pragma unroll
        for (int j = 0; j < TPS; ++j) {
            const char* p0 = base + j * 2048;
            short8 a0 = *(const short8*)(p0);
            short8 a1 = *(const short8*)(p0 + 1024);
            float4 cc = *(const float4*)(ckS + j * 16);

            v4f acc = {0.f, 0.f, 0.f, 0.f};
            acc = __builtin_amdgcn_mfma_f32_16x16x32_bf16(a0, bh0, acc, 0, 0, 0);
            acc = __builtin_amdgcn_mfma_f32_16x16x32_bf16(a1, bh1, acc, 0, 0, 0);
            acc = __builtin_amdgcn_mfma_f32_16x16x32_bf16(a0, bl0, acc, 0, 0, 0);
            acc = __builtin_amdgcn_mfma_f32_16x16x32_bf16(a1, bl1, acc, 0, 0, 0);

            const int kb = kb0 + j * 16;
            float w0 = fmaf(acc.x, S2C, cc.x);
            float w1 = fmaf(acc.y, S2C, cc.y);
            float w2 = fmaf(acc.z, S2C, cc.z);
            float w3 = fmaf(acc.w, S2C, cc.w);
            s0 += EXP2(w0) + EXP2(w1);
            s1 += EXP2(w2) + EXP2(w3);

            // tile-granular top-3 (the 4 values share quad-base kb)
            float T4 = fmaxf(fmaxf(w0, w1), fmaxf(w2, w3));
            bool c = T4 > m1;
            float z = fminf(T4, m1);
            int zi = c ? i1 : kb;
            m1 = fmaxf(T4, m1);
            i1 = c ? kb : i1;
            float m3old = m3;
            bool c2 = z > m2;
            m3 = med3f(z, m2, m3);
            i3 = c2 ? i2 : ((z > m3old) ? zi : i3);
            m2 = fmaxf(z, m2);
            i2 = c2 ? zi : i2;
        }
        __syncthreads();
    }

    // ---- merge the 4 quads (disjoint comp subsets, same sample col n)
    float sum = s0 + s1;
#pragma unroll
    for (int d = 16; d <= 32; d <<= 1) {
        sum += __shfl_xor(sum, d);
        float M1 = __shfl_xor(m1, d), M2 = __shfl_xor(m2, d), M3 = __shfl_xor(m3, d);
        int   I1 = __shfl_xor(i1, d), I2 = __shfl_xor(i2, d), I3 = __shfl_xor(i3, d);
        bool cc = (M1 > m1) || (M1 == m1 && I1 < i1);
        float w2v = cc ? M2 : m2;  int w2i = cc ? I2 : i2;
        float w3v = cc ? M3 : m3;  int w3i = cc ? I3 : i3;
        float lv  = cc ? m1 : M1;  int li  = cc ? i1 : I1;
        float l2v = cc ? m2 : M2;  int l2i = cc ? i2 : I2;
        m1 = cc ? M1 : m1;  i1 = cc ? I1 : i1;
        bool c2 = lv > w2v;
        float nm2 = c2 ? lv : w2v;  int ni2 = c2 ? li : w2i;
        float z3 = c2 ? w2v : lv;   int zi3 = c2 ? w2i : li;
        float nm3 = fmaxf(z3, fmaxf(w3v, l2v));
        int ni3 = (z3 >= w3v && z3 >= l2v) ? zi3 : ((w3v >= l2v) ? w3i : l2i);
        m2 = nm2; i2 = ni2; m3 = nm3; i3 = ni3;
    }

    if (quad == 0) {
        float bias = -xs * (1.0f / 128.0f) - LNC;
        out[srow] = fmaf(__log2f(sum), LN2F, bias - lse_ptr[0]);
        int s = wv * 16 + n;
        cb1[s] = i1; cb2[s] = i2; cb3[s] = i3;
    }
    __syncthreads();

    // ---- exact resolution: 12 candidates per sample, fp32 dot + ck2,
    // argmax with first-occurrence (smallest k) tie semantics.
    {
        int s = tid >> 2;        // 0..63
        int jj = tid & 3;        // candidate offset within each quad-base
        const float4* xrow = (const float4*)(x + (size_t)(sbase + s) * ZD);
        float bestv = -1e30f;
        int bestk = 0x7fffffff;
        int bases[3] = {cb1[s], cb2[s], cb3[s]};
#pragma unroll
        for (int ci = 0; ci < 3; ++ci) {
            int k = bases[ci] + jj;
            const float4* lrow = (const float4*)(locs + (size_t)k * ZD);
            float dot = 0.f;
#pragma unroll
            for (int dd = 0; dd < 16; ++dd) {
                float4 xv = xrow[dd];
                float4 lv = lrow[dd];
                dot = fmaf(xv.x, lv.x, dot);
                dot = fmaf(xv.y, lv.y, dot);
                dot = fmaf(xv.z, lv.z, dot);
                dot = fmaf(xv.w, lv.w, dot);
            }
            float v = fmaf(dot, S2C, ck2[k]);
            if (v > bestv || (v == bestv && k < bestk)) { bestv = v; bestk = k; }
        }
#pragma unroll
        for (int d = 1; d <= 2; d <<= 1) {
            float ov = __shfl_xor(bestv, d);
            int   ok = __shfl_xor(bestk, d);
            if (ov > bestv || (ov == bestv && ok < bestk)) { bestv = ov; bestk = ok; }
        }
        if (jj == 0) amax_sh[s] = bestk;
    }
    __syncthreads();

    // ---- quantized = locs[argmax], cooperative coalesced float4 writes
    const float4* lq = (const float4*)locs;
    float4* oq = (float4*)(out + N_SAMP + (size_t)sbase * ZD);
#pragma unroll
    for (int i = tid; i < 64 * (ZD / 4); i += 256) {
        int r = i >> 4, c = i & 15;
        oq[i] = lq[(size_t)amax_sh[r] * (ZD / 4) + c];
    }
#undef DMA
}

extern "C" void kernel_launch(void* const* d_in, const int* in_sizes, int n_in,
                              void* d_out, int out_size, void* d_ws, size_t ws_size,
                              hipStream_t stream) {
    const float* x      = (const float*)d_in[0];
    const float* locs   = (const float*)d_in[1];
    const float* logits = (const float*)d_in[2];
    float* out = (float*)d_out;

    float* ck2 = (float*)d_ws;                 // 2048 floats
    float* lse = (float*)((char*)d_ws + 8192); // 1 float
    char*  lf  = (char*)d_ws + 16384;          // 256 KB hi-frag array

    prep_kernel<<<65, 256, 0, stream>>>(locs, logits, ck2, lse, lf);
    mix_kernel<<<N_SAMP / 64, 256, 0, stream>>>(x, locs, lf, ck2, lse, out);
}

// Round 8
// 105.958 us; speedup vs baseline: 1.1170x; 1.1170x over previous
//
#include <hip/hip_runtime.h>
#include <math.h>

#define N_SAMP 32768
#define K_COMP 2048
#define ZD 64
#define LNC 191.896324792608546f   // 64*(0.5*log(2pi) + 0.5*log(64))
#define LN2F 0.69314718055994531f
#define INV_LN2 1.44269504088896340f
// w = dot*(1/(64 ln2)) + ck2 ; wlp_nat = w*ln2 + bias_nat
#define S2C 0.02254211001388974f   // 1/(64*ln2)

#define STAGES 16                  // 64 tiles per kg / 4 tiles per stage
#define STAGE_B 16384              // 8 tiles x 2 KB

typedef __attribute__((ext_vector_type(8))) short short8;
typedef __attribute__((ext_vector_type(4))) float v4f;

#if __has_builtin(__builtin_amdgcn_exp2f)
#define EXP2(x) __builtin_amdgcn_exp2f(x)
#else
#define EXP2(x) exp2f(x)
#endif

typedef const __attribute__((address_space(1))) unsigned int* gas_t;
typedef __attribute__((address_space(3))) unsigned int* las_t;
__device__ inline void gload_lds16(const void* g, void* l) {
    __builtin_amdgcn_global_load_lds((gas_t)g, (las_t)l, 16, 0, 0);
}

__device__ inline unsigned short f2bf(float f) {
    unsigned int u = __float_as_uint(f);
    u += 0x7fffu + ((u >> 16) & 1u);  // RNE
    return (unsigned short)(u >> 16);
}
__device__ inline float bf2f(unsigned short h) {
    return __uint_as_float(((unsigned int)h) << 16);
}

// ---------------------------------------------------------------------------
// prep: blocks 0..63: locs -> bf16-HI fragment array lf (256 KB) + ck2.
//       block 64: lse = logsumexp(logits).
// lf: tile T (16 comps) -> 2 KB: 2 regions {d0-31, d32-63} x 64 lanes x 16 B.
// ---------------------------------------------------------------------------
__global__ __launch_bounds__(256) void prep_kernel(
    const float* __restrict__ locs, const float* __restrict__ logits,
    float* __restrict__ ck2, float* __restrict__ lse_out,
    char* __restrict__ lf) {
    if (blockIdx.x < 64) {
        int gid = blockIdx.x * 256 + threadIdx.x;   // 0..16383
        int k = gid >> 3;
        int dc = gid & 7;
        int T = k >> 4, n = k & 15;

        const float* src = locs + (size_t)k * ZD + dc * 8;
        float4 u0 = *(const float4*)(src);
        float4 u1 = *(const float4*)(src + 4);
        float a[8] = {u0.x, u0.y, u0.z, u0.w, u1.x, u1.y, u1.z, u1.w};

        short8 h;
        float sq = 0.f;
#pragma unroll
        for (int j = 0; j < 8; ++j) {
            h[j] = (short)f2bf(a[j]);
            sq = fmaf(a[j], a[j], sq);
        }
        *(short8*)(lf + (size_t)T * 2048 + (dc >> 2) * 1024 +
                   ((size_t)(n + 16 * (dc & 3))) * 16) = h;

        sq += __shfl_xor(sq, 1);
        sq += __shfl_xor(sq, 2);
        sq += __shfl_xor(sq, 4);
        if (dc == 0) ck2[k] = (logits[k] - sq * (1.0f / 128.0f)) * INV_LN2;
    } else {
        __shared__ float red[4];
        int tid = threadIdx.x;
        int wv = tid >> 6, ln = tid & 63;
        float lm = -INFINITY;
        for (int i = tid; i < K_COMP; i += 256) lm = fmaxf(lm, logits[i]);
#pragma unroll
        for (int d = 1; d < 64; d <<= 1) lm = fmaxf(lm, __shfl_xor(lm, d));
        if (ln == 0) red[wv] = lm;
        __syncthreads();
        float M = fmaxf(fmaxf(red[0], red[1]), fmaxf(red[2], red[3]));
        float ls = 0.f;
        for (int i = tid; i < K_COMP; i += 256) ls += __expf(logits[i] - M);
#pragma unroll
        for (int d = 1; d < 64; d <<= 1) ls += __shfl_xor(ls, d);
        __syncthreads();
        if (ln == 0) red[wv] = ls;
        __syncthreads();
        if (tid == 0) *lse_out = M + __logf(red[0] + red[1] + red[2] + red[3]);
    }
}

// ---------------------------------------------------------------------------
// mix: block = 512 thr = 8 waves = 4 sample-groups(16 samp) x 2 k-groups
// (64 tiles each) -> 16 waves/CU = 4 waves/SIMD.  LDS-DMA double-buffered
// stages of 16 KB (8 tiles; wave w stages tile (w>>2)*64+4S+(w&3)).
// Per wave-stage: 4 tiles as 2 ILP pairs, each pair = 2 independent 4-MFMA
// chains (hi-only locs x split-x).  Flat exp2-sum + top-3 quad-base insert;
// exact fp32 resolution of the 12 candidates afterwards.
// ---------------------------------------------------------------------------
__global__ __launch_bounds__(512, 4) void mix_kernel(
    const float* __restrict__ x, const float* __restrict__ locs,
    const char* __restrict__ lf, const float* __restrict__ ck2,
    const float* __restrict__ lse_ptr, float* __restrict__ out) {

    __shared__ char buf[2][STAGE_B];       // 2 x 16 KB
    __shared__ float wm1[2][64], wm2[2][64], wm3[2][64], wsum[2][64];
    __shared__ int   wi1[2][64], wi2[2][64], wi3[2][64];
    __shared__ float xsq_sh[64];
    __shared__ int   cb[3][64];
    __shared__ int   amax_sh[64];

    const int tid  = threadIdx.x;
    const int lane = tid & 63;
    const int wv   = __builtin_amdgcn_readfirstlane(tid >> 6);  // 0..7
    const int sg   = __builtin_amdgcn_readfirstlane(wv & 3);
    const int kg   = __builtin_amdgcn_readfirstlane(wv >> 2);
    const int n    = lane & 15;
    const int quad = lane >> 4;
    const int sbase = blockIdx.x * 64;
    const int srow  = sbase + sg * 16 + n;

    // ---- B fragments (x) hi/lo split; ||x||^2 exact fp32
    short8 bh0, bh1, bl0, bl1;
    {
        const float* xp = x + (size_t)srow * ZD + quad * 8;
        float4 u0 = *(const float4*)(xp);
        float4 u1 = *(const float4*)(xp + 4);
        float4 u2 = *(const float4*)(xp + 32);
        float4 u3 = *(const float4*)(xp + 36);
        float a[8] = {u0.x, u0.y, u0.z, u0.w, u1.x, u1.y, u1.z, u1.w};
        float b[8] = {u2.x, u2.y, u2.z, u2.w, u3.x, u3.y, u3.z, u3.w};
        float p = 0.f;
#pragma unroll
        for (int j = 0; j < 8; ++j) {
            unsigned short h;
            h = f2bf(a[j]); bh0[j] = (short)h; bl0[j] = (short)f2bf(a[j] - bf2f(h));
            h = f2bf(b[j]); bh1[j] = (short)h; bl1[j] = (short)f2bf(b[j] - bf2f(h));
            p = fmaf(a[j], a[j], p);
            p = fmaf(b[j], b[j], p);
        }
        p += __shfl_xor(p, 16);
        p += __shfl_xor(p, 32);
        if (kg == 0 && quad == 0) xsq_sh[sg * 16 + n] = p;
    }

    // ---- DMA: wave wv stages global tile (wv>>2)*64 + 4S + (wv&3) -> slot wv
    const char* gsrc0 = lf + (size_t)((wv >> 2) * 64 + (wv & 3)) * 2048 + lane * 16;
    char* ldst0 = &buf[0][wv * 2048];

#define DMA(S, b) do {                                                   \
    const char* _g = gsrc0 + (size_t)(S) * (4 * 2048);                   \
    char* _l = ldst0 + (b) * STAGE_B;                                    \
    gload_lds16(_g, _l);                                                 \
    gload_lds16(_g + 1024, _l + 1024);                                   \
} while (0)

    float m1 = -1e30f, m2 = -1e30f, m3 = -1e30f;
    int i1 = 0, i2 = 0, i3 = 0;
    float s0 = 0.f, s1 = 0.f;

    // top-3 insert of (v, kb)
#define INS(v, kb) do {                                                  \
    bool c1 = (v) > m1, c2 = (v) > m2, c3 = (v) > m3;                    \
    m3 = c2 ? m2 : (c3 ? (v) : m3);  i3 = c2 ? i2 : (c3 ? (kb) : i3);    \
    m2 = c1 ? m1 : (c2 ? (v) : m2);  i2 = c1 ? i1 : (c2 ? (kb) : i2);    \
    m1 = c1 ? (v) : m1;              i1 = c1 ? (kb) : i1;                \
} while (0)

#define EPI(acc, cc, kb) do {                                            \
    float w0 = fmaf((acc).x, S2C, (cc).x);                               \
    float w1 = fmaf((acc).y, S2C, (cc).y);                               \
    float w2 = fmaf((acc).z, S2C, (cc).z);                               \
    float w3 = fmaf((acc).w, S2C, (cc).w);                               \
    s0 += EXP2(w0) + EXP2(w1);                                           \
    s1 += EXP2(w2) + EXP2(w3);                                           \
    float v4 = fmaxf(fmaxf(w0, w1), fmaxf(w2, w3));                      \
    INS(v4, kb);                                                         \
} while (0)

    DMA(0, 0);
    __syncthreads();

    for (int S = 0; S < STAGES; ++S) {
        const int b = S & 1;
        if (S + 1 < STAGES) DMA(S + 1, b ^ 1);

        const int tb = kg * 64 + 4 * S;               // first tile this wave eats
        const float* ckS = ck2 + tb * 16 + quad * 4;
        const char* base = &buf[b][(kg * 4) * 2048 + lane * 16];
        const int kb0 = tb * 16 + quad * 4;

#pragma unroll
        for (int jp = 0; jp < 4; jp += 2) {
            const char* p0 = base + jp * 2048;
            const char* p1 = p0 + 2048;
            short8 a00 = *(const short8*)(p0);
            short8 a01 = *(const short8*)(p0 + 1024);
            short8 a10 = *(const short8*)(p1);
            short8 a11 = *(const short8*)(p1 + 1024);
            float4 cc0 = *(const float4*)(ckS + jp * 16);
            float4 cc1 = *(const float4*)(ckS + jp * 16 + 16);

            v4f ca = {0.f, 0.f, 0.f, 0.f};
            v4f cb2_ = {0.f, 0.f, 0.f, 0.f};
            ca   = __builtin_amdgcn_mfma_f32_16x16x32_bf16(a00, bh0, ca, 0, 0, 0);
            cb2_ = __builtin_amdgcn_mfma_f32_16x16x32_bf16(a10, bh0, cb2_, 0, 0, 0);
            ca   = __builtin_amdgcn_mfma_f32_16x16x32_bf16(a01, bh1, ca, 0, 0, 0);
            cb2_ = __builtin_amdgcn_mfma_f32_16x16x32_bf16(a11, bh1, cb2_, 0, 0, 0);
            ca   = __builtin_amdgcn_mfma_f32_16x16x32_bf16(a00, bl0, ca, 0, 0, 0);
            cb2_ = __builtin_amdgcn_mfma_f32_16x16x32_bf16(a10, bl0, cb2_, 0, 0, 0);
            ca   = __builtin_amdgcn_mfma_f32_16x16x32_bf16(a01, bl1, ca, 0, 0, 0);
            cb2_ = __builtin_amdgcn_mfma_f32_16x16x32_bf16(a11, bl1, cb2_, 0, 0, 0);

            EPI(ca,   cc0, kb0 + jp * 16);
            EPI(cb2_, cc1, kb0 + jp * 16 + 16);
        }
        __syncthreads();
    }

    // ---- merge the 4 quads (disjoint comp subsets, same sample col n)
    float sum = s0 + s1;
#pragma unroll
    for (int d = 16; d <= 32; d <<= 1) {
        sum += __shfl_xor(sum, d);
        float M1 = __shfl_xor(m1, d), M2 = __shfl_xor(m2, d), M3 = __shfl_xor(m3, d);
        int   I1 = __shfl_xor(i1, d), I2 = __shfl_xor(i2, d), I3 = __shfl_xor(i3, d);
        INS(M1, I1); INS(M2, I2); INS(M3, I3);
    }
    if (quad == 0) {
        int s = sg * 16 + n;
        wm1[kg][s] = m1; wm2[kg][s] = m2; wm3[kg][s] = m3;
        wi1[kg][s] = i1; wi2[kg][s] = i2; wi3[kg][s] = i3;
        wsum[kg][s] = sum;
    }
    __syncthreads();

    // ---- merge the 2 k-groups (tid<64), write log_prob, stash bases
    if (tid < 64) {
        float m1 = wm1[0][tid], m2 = wm2[0][tid], m3 = wm3[0][tid];
        int   i1 = wi1[0][tid], i2 = wi2[0][tid], i3 = wi3[0][tid];
        INS(wm1[1][tid], wi1[1][tid]);
        INS(wm2[1][tid], wi2[1][tid]);
        INS(wm3[1][tid], wi3[1][tid]);
        float S = wsum[0][tid] + wsum[1][tid];
        float bias = -xsq_sh[tid] * (1.0f / 128.0f) - LNC;
        out[sbase + tid] = fmaf(__log2f(S), LN2F, bias - lse_ptr[0]);
        cb[0][tid] = i1; cb[1][tid] = i2; cb[2][tid] = i3;
    }
    __syncthreads();

    // ---- exact resolution: 12 candidates/sample, fp32, first-tie smallest k
    {
        int s = tid >> 3;        // 0..63
        int j = tid & 7;
        const float4* xrow = (const float4*)(x + (size_t)(sbase + s) * ZD);
        float bestv = -1e30f;
        int bestk = 0x7fffffff;
#pragma unroll
        for (int ci = j; ci < 12; ci += 8) {
            int k = cb[ci >> 2][s] + (ci & 3);
            const float4* lrow = (const float4*)(locs + (size_t)k * ZD);
            float dot = 0.f;
#pragma unroll
            for (int dd = 0; dd < 16; ++dd) {
                float4 xv = xrow[dd];
                float4 lv = lrow[dd];
                dot = fmaf(xv.x, lv.x, dot);
                dot = fmaf(xv.y, lv.y, dot);
                dot = fmaf(xv.z, lv.z, dot);
                dot = fmaf(xv.w, lv.w, dot);
            }
            float v = fmaf(dot, S2C, ck2[k]);
            if (v > bestv || (v == bestv && k < bestk)) { bestv = v; bestk = k; }
        }
#pragma unroll
        for (int d = 1; d <= 4; d <<= 1) {
            float ov = __shfl_xor(bestv, d);
            int   ok = __shfl_xor(bestk, d);
            if (ov > bestv || (ov == bestv && ok < bestk)) { bestv = ov; bestk = ok; }
        }
        if (j == 0) amax_sh[s] = bestk;
    }
    __syncthreads();

    // ---- quantized = locs[argmax], cooperative coalesced float4 writes
    const float4* lq = (const float4*)locs;
    float4* oq = (float4*)(out + N_SAMP + (size_t)sbase * ZD);
#pragma unroll
    for (int i = tid; i < 64 * (ZD / 4); i += 512) {
        int r = i >> 4, c = i & 15;
        oq[i] = lq[(size_t)amax_sh[r] * (ZD / 4) + c];
    }
#undef DMA
#undef INS
#undef EPI
}

extern "C" void kernel_launch(void* const* d_in, const int* in_sizes, int n_in,
                              void* d_out, int out_size, void* d_ws, size_t ws_size,
                              hipStream_t stream) {
    const float* x      = (const float*)d_in[0];
    const float* locs   = (const float*)d_in[1];
    const float* logits = (const float*)d_in[2];
    float* out = (float*)d_out;

    float* ck2 = (float*)d_ws;                 // 2048 floats
    float* lse = (float*)((char*)d_ws + 8192); // 1 float
    char*  lf  = (char*)d_ws + 16384;          // 256 KB hi-frag array

    prep_kernel<<<65, 256, 0, stream>>>(locs, logits, ck2, lse, lf);
    mix_kernel<<<N_SAMP / 64, 512, 0, stream>>>(x, locs, lf, ck2, lse, out);
}

// Round 9
// 103.932 us; speedup vs baseline: 1.1388x; 1.0195x over previous
//
#include <hip/hip_runtime.h>
#include <math.h>

#define N_SAMP 32768
#define K_COMP 2048
#define ZD 64
#define LNC 191.896324792608546f   // 64*(0.5*log(2pi) + 0.5*log(64))
#define LN2F 0.69314718055994531f
#define INV_LN2 1.44269504088896340f
// w = dot*(1/(64 ln2)) + ck2 ; wlp_nat = w*ln2 + bias_nat
#define S2C 0.02254211001388974f   // 1/(64*ln2)

typedef __attribute__((ext_vector_type(8))) short short8;
typedef __attribute__((ext_vector_type(4))) float v4f;

#if __has_builtin(__builtin_amdgcn_exp2f)
#define EXP2(x) __builtin_amdgcn_exp2f(x)
#else
#define EXP2(x) exp2f(x)
#endif

__device__ inline unsigned short f2bf(float f) {
    unsigned int u = __float_as_uint(f);
    u += 0x7fffu + ((u >> 16) & 1u);  // RNE
    return (unsigned short)(u >> 16);
}

// ---------------------------------------------------------------------------
// prep: blocks 0..63: locs -> bf16-HI fragment array lf (256 KB) + ck2.
//       block 64: lse = logsumexp(logits).
// lf: tile T (16 comps) -> 2 KB: 2 regions {d0-31, d32-63} x 64 lanes x 16 B.
// ---------------------------------------------------------------------------
__global__ __launch_bounds__(256) void prep_kernel(
    const float* __restrict__ locs, const float* __restrict__ logits,
    float* __restrict__ ck2, float* __restrict__ lse_out,
    char* __restrict__ lf) {
    if (blockIdx.x < 64) {
        int gid = blockIdx.x * 256 + threadIdx.x;   // 0..16383
        int k = gid >> 3;
        int dc = gid & 7;
        int T = k >> 4, n = k & 15;

        const float* src = locs + (size_t)k * ZD + dc * 8;
        float4 u0 = *(const float4*)(src);
        float4 u1 = *(const float4*)(src + 4);
        float a[8] = {u0.x, u0.y, u0.z, u0.w, u1.x, u1.y, u1.z, u1.w};

        short8 h;
        float sq = 0.f;
#pragma unroll
        for (int j = 0; j < 8; ++j) {
            h[j] = (short)f2bf(a[j]);
            sq = fmaf(a[j], a[j], sq);
        }
        *(short8*)(lf + (size_t)T * 2048 + (dc >> 2) * 1024 +
                   ((size_t)(n + 16 * (dc & 3))) * 16) = h;

        sq += __shfl_xor(sq, 1);
        sq += __shfl_xor(sq, 2);
        sq += __shfl_xor(sq, 4);
        if (dc == 0) ck2[k] = (logits[k] - sq * (1.0f / 128.0f)) * INV_LN2;
    } else {
        __shared__ float red[4];
        int tid = threadIdx.x;
        int wv = tid >> 6, ln = tid & 63;
        float lm = -INFINITY;
        for (int i = tid; i < K_COMP; i += 256) lm = fmaxf(lm, logits[i]);
#pragma unroll
        for (int d = 1; d < 64; d <<= 1) lm = fmaxf(lm, __shfl_xor(lm, d));
        if (ln == 0) red[wv] = lm;
        __syncthreads();
        float M = fmaxf(fmaxf(red[0], red[1]), fmaxf(red[2], red[3]));
        float ls = 0.f;
        for (int i = tid; i < K_COMP; i += 256) ls += __expf(logits[i] - M);
#pragma unroll
        for (int d = 1; d < 64; d <<= 1) ls += __shfl_xor(ls, d);
        __syncthreads();
        if (ln == 0) red[wv] = ls;
        __syncthreads();
        if (tid == 0) *lse_out = M + __logf(red[0] + red[1] + red[2] + red[3]);
    }
}

// ---------------------------------------------------------------------------
// mix: block = 512 thr = 8 waves = 8 K-GROUPS over the SAME 32 samples.
// Each wave: fully independent register ring-2 over its 16 tiles (1-pass
// bf16 MFMA: 2 per tile per sample-group), flat exp2-sum + top-3 quad-base
// tracking. NO in-loop barriers. One __syncthreads, LDS merge of 8 partials,
// exact-fp32 resolution of 12 candidates, gather.
// ---------------------------------------------------------------------------
__global__ __launch_bounds__(512, 6) void mix_kernel(
    const float* __restrict__ x, const float* __restrict__ locs,
    const char* __restrict__ lf, const float* __restrict__ ck2,
    const float* __restrict__ lse_ptr, float* __restrict__ out) {

    __shared__ float pf[8][32][4];   // [kg][samp][{sum,m1,m2,m3}]
    __shared__ int   pi[8][32][4];   // [kg][samp][{i1,i2,i3,pad}]
    __shared__ float xsq_sh[32];
    __shared__ int   cb[3][32];
    __shared__ int   amax_sh[32];

    const int tid  = threadIdx.x;
    const int lane = tid & 63;
    const int kg   = __builtin_amdgcn_readfirstlane(tid >> 6);  // 0..7
    const int n    = lane & 15;
    const int quad = lane >> 4;
    const int sbase = blockIdx.x * 32;

    // ---- B fragments (x, plain bf16) for sample tiles 0 (n) and 1 (16+n)
    short8 bh0, bh1, bh2, bh3;
    {
        const float* xp = x + (size_t)(sbase + n) * ZD + quad * 8;
        float4 u0 = *(const float4*)(xp);
        float4 u1 = *(const float4*)(xp + 4);
        float4 u2 = *(const float4*)(xp + 32);
        float4 u3 = *(const float4*)(xp + 36);
        const float* yp = x + (size_t)(sbase + 16 + n) * ZD + quad * 8;
        float4 v0 = *(const float4*)(yp);
        float4 v1 = *(const float4*)(yp + 4);
        float4 v2 = *(const float4*)(yp + 32);
        float4 v3 = *(const float4*)(yp + 36);
        float a[8] = {u0.x, u0.y, u0.z, u0.w, u1.x, u1.y, u1.z, u1.w};
        float b[8] = {u2.x, u2.y, u2.z, u2.w, u3.x, u3.y, u3.z, u3.w};
        float c[8] = {v0.x, v0.y, v0.z, v0.w, v1.x, v1.y, v1.z, v1.w};
        float d[8] = {v2.x, v2.y, v2.z, v2.w, v3.x, v3.y, v3.z, v3.w};
        float pA = 0.f, pB = 0.f;
#pragma unroll
        for (int j = 0; j < 8; ++j) {
            bh0[j] = (short)f2bf(a[j]);
            bh1[j] = (short)f2bf(b[j]);
            bh2[j] = (short)f2bf(c[j]);
            bh3[j] = (short)f2bf(d[j]);
            pA = fmaf(a[j], a[j], pA); pA = fmaf(b[j], b[j], pA);
            pB = fmaf(c[j], c[j], pB); pB = fmaf(d[j], d[j], pB);
        }
        pA += __shfl_xor(pA, 16); pA += __shfl_xor(pA, 32);
        pB += __shfl_xor(pB, 16); pB += __shfl_xor(pB, 32);
        if (kg == 0) {
            if (quad == 0) xsq_sh[n] = pA;
            if (quad == 1) xsq_sh[16 + n] = pB;
        }
    }

    // ---- A stream: wave kg owns tiles kg*16 .. kg*16+15, register ring-2
    const char* aw = lf + (size_t)(kg * 16) * 2048 + lane * 16;
    const float* ckw = ck2 + kg * 256 + quad * 4;
    const int kb0 = kg * 256 + quad * 4;

    short8 fa[2][2];
    float4 fc[2];

#define LOADA(slot, t) do {                                              \
    const char* _p = aw + (size_t)(t) * 2048;                            \
    fa[slot][0] = *(const short8*)(_p);                                  \
    fa[slot][1] = *(const short8*)(_p + 1024);                           \
    fc[slot] = *(const float4*)(ckw + (t) * 16);                         \
} while (0)

    float sA = 0.f, m1A = -1e30f, m2A = -1e30f, m3A = -1e30f;
    int i1A = 0, i2A = 0, i3A = 0;
    float sB = 0.f, m1B = -1e30f, m2B = -1e30f, m3B = -1e30f;
    int i1B = 0, i2B = 0, i3B = 0;

#define INS(m1, m2, m3, i1, i2, i3, v, kb) do {                          \
    bool c1 = (v) > m1, c2 = (v) > m2, c3 = (v) > m3;                    \
    m3 = c2 ? m2 : (c3 ? (v) : m3);  i3 = c2 ? i2 : (c3 ? (kb) : i3);    \
    m2 = c1 ? m1 : (c2 ? (v) : m2);  i2 = c1 ? i1 : (c2 ? (kb) : i2);    \
    m1 = c1 ? (v) : m1;              i1 = c1 ? (kb) : i1;                \
} while (0)

#define EPI(acc, cc, kb, S, M1, M2, M3, I1, I2, I3) do {                 \
    float w0 = fmaf((acc).x, S2C, (cc).x);                               \
    float w1 = fmaf((acc).y, S2C, (cc).y);                               \
    float w2 = fmaf((acc).z, S2C, (cc).z);                               \
    float w3 = fmaf((acc).w, S2C, (cc).w);                               \
    S += (EXP2(w0) + EXP2(w1)) + (EXP2(w2) + EXP2(w3));                  \
    float v4 = fmaxf(fmaxf(w0, w1), fmaxf(w2, w3));                      \
    INS(M1, M2, M3, I1, I2, I3, v4, kb);                                 \
} while (0)

    LOADA(0, 0);
#pragma unroll
    for (int t = 0; t < 16; ++t) {
        const int slot = t & 1;
        if (t + 1 < 16) LOADA(slot ^ 1, t + 1);

        v4f accA = {0.f, 0.f, 0.f, 0.f};
        v4f accB = {0.f, 0.f, 0.f, 0.f};
        accA = __builtin_amdgcn_mfma_f32_16x16x32_bf16(fa[slot][0], bh0, accA, 0, 0, 0);
        accB = __builtin_amdgcn_mfma_f32_16x16x32_bf16(fa[slot][0], bh2, accB, 0, 0, 0);
        accA = __builtin_amdgcn_mfma_f32_16x16x32_bf16(fa[slot][1], bh1, accA, 0, 0, 0);
        accB = __builtin_amdgcn_mfma_f32_16x16x32_bf16(fa[slot][1], bh3, accB, 0, 0, 0);

        const int kb = kb0 + t * 16;
        float4 cc = fc[slot];
        EPI(accA, cc, kb, sA, m1A, m2A, m3A, i1A, i2A, i3A);
        EPI(accB, cc, kb, sB, m1B, m2B, m3B, i1B, i2B, i3B);
    }

    // ---- merge the 4 quads (disjoint comp subsets, same sample column)
#pragma unroll
    for (int d = 16; d <= 32; d <<= 1) {
        sA += __shfl_xor(sA, d);
        sB += __shfl_xor(sB, d);
        float M1, M2, M3; int I1, I2, I3;
        M1 = __shfl_xor(m1A, d); M2 = __shfl_xor(m2A, d); M3 = __shfl_xor(m3A, d);
        I1 = __shfl_xor(i1A, d); I2 = __shfl_xor(i2A, d); I3 = __shfl_xor(i3A, d);
        INS(m1A, m2A, m3A, i1A, i2A, i3A, M1, I1);
        INS(m1A, m2A, m3A, i1A, i2A, i3A, M2, I2);
        INS(m1A, m2A, m3A, i1A, i2A, i3A, M3, I3);
        M1 = __shfl_xor(m1B, d); M2 = __shfl_xor(m2B, d); M3 = __shfl_xor(m3B, d);
        I1 = __shfl_xor(i1B, d); I2 = __shfl_xor(i2B, d); I3 = __shfl_xor(i3B, d);
        INS(m1B, m2B, m3B, i1B, i2B, i3B, M1, I1);
        INS(m1B, m2B, m3B, i1B, i2B, i3B, M2, I2);
        INS(m1B, m2B, m3B, i1B, i2B, i3B, M3, I3);
    }
    if (quad == 0) {
        pf[kg][n][0] = sA; pf[kg][n][1] = m1A; pf[kg][n][2] = m2A; pf[kg][n][3] = m3A;
        pi[kg][n][0] = i1A; pi[kg][n][1] = i2A; pi[kg][n][2] = i3A;
        pf[kg][16 + n][0] = sB; pf[kg][16 + n][1] = m1B;
        pf[kg][16 + n][2] = m2B; pf[kg][16 + n][3] = m3B;
        pi[kg][16 + n][0] = i1B; pi[kg][16 + n][1] = i2B; pi[kg][16 + n][2] = i3B;
    }
    __syncthreads();

    // ---- merge 8 k-groups (tid<32), write log_prob, stash top-3 bases
    if (tid < 32) {
        float S = 0.f, m1 = -1e30f, m2 = -1e30f, m3 = -1e30f;
        int i1 = 0, i2 = 0, i3 = 0;
#pragma unroll
        for (int g = 0; g < 8; ++g) {   // ascending kg => first-tie kept
            S += pf[g][tid][0];
            INS(m1, m2, m3, i1, i2, i3, pf[g][tid][1], pi[g][tid][0]);
            INS(m1, m2, m3, i1, i2, i3, pf[g][tid][2], pi[g][tid][1]);
            INS(m1, m2, m3, i1, i2, i3, pf[g][tid][3], pi[g][tid][2]);
        }
        float bias = -xsq_sh[tid] * (1.0f / 128.0f) - LNC;
        out[sbase + tid] = fmaf(__log2f(S), LN2F, bias - lse_ptr[0]);
        cb[0][tid] = i1; cb[1][tid] = i2; cb[2][tid] = i3;
    }
    __syncthreads();

    // ---- exact resolution: 12 candidates/sample, fp32, first-tie smallest k
    if (tid < 256) {
        int s = tid >> 3;        // 0..31
        int j = tid & 7;
        const float4* xrow = (const float4*)(x + (size_t)(sbase + s) * ZD);
        float bestv = -1e30f;
        int bestk = 0x7fffffff;
#pragma unroll
        for (int ci = j; ci < 12; ci += 8) {
            int k = cb[ci >> 2][s] + (ci & 3);
            const float4* lrow = (const float4*)(locs + (size_t)k * ZD);
            float dot = 0.f;
#pragma unroll
            for (int dd = 0; dd < 16; ++dd) {
                float4 xv = xrow[dd];
                float4 lv = lrow[dd];
                dot = fmaf(xv.x, lv.x, dot);
                dot = fmaf(xv.y, lv.y, dot);
                dot = fmaf(xv.z, lv.z, dot);
                dot = fmaf(xv.w, lv.w, dot);
            }
            float v = fmaf(dot, S2C, ck2[k]);
            if (v > bestv || (v == bestv && k < bestk)) { bestv = v; bestk = k; }
        }
#pragma unroll
        for (int d = 1; d <= 4; d <<= 1) {
            float ov = __shfl_xor(bestv, d);
            int   ok = __shfl_xor(bestk, d);
            if (ov > bestv || (ov == bestv && ok < bestk)) { bestv = ov; bestk = ok; }
        }
        if (j == 0) amax_sh[s] = bestk;
    }
    __syncthreads();

    // ---- quantized = locs[argmax]: 32 rows x 16 float4 = 512 = blockDim
    {
        const float4* lq = (const float4*)locs;
        float4* oq = (float4*)(out + N_SAMP + (size_t)sbase * ZD);
        int r = tid >> 4, c = tid & 15;
        oq[tid] = lq[(size_t)amax_sh[r] * (ZD / 4) + c];
    }
#undef LOADA
#undef INS
#undef EPI
}

extern "C" void kernel_launch(void* const* d_in, const int* in_sizes, int n_in,
                              void* d_out, int out_size, void* d_ws, size_t ws_size,
                              hipStream_t stream) {
    const float* x      = (const float*)d_in[0];
    const float* locs   = (const float*)d_in[1];
    const float* logits = (const float*)d_in[2];
    float* out = (float*)d_out;

    float* ck2 = (float*)d_ws;                 // 2048 floats
    float* lse = (float*)((char*)d_ws + 8192); // 1 float
    char*  lf  = (char*)d_ws + 16384;          // 256 KB hi-frag array

    prep_kernel<<<65, 256, 0, stream>>>(locs, logits, ck2, lse, lf);
    mix_kernel<<<N_SAMP / 32, 512, 0, stream>>>(x, locs, lf, ck2, lse, out);
}